// Round 5
// baseline (131.922 us; speedup 1.0000x reference)
//
#include <hip/hip_runtime.h>
#include <cstdint>

// Problem constants: B=32, T=D=256, rows R = B*T = 8192, K = 256.
#define R_TOT 8192
#define KD    256
#define SLOT  ((size_t)R_TOT * KD)            // bytes per fp8 image (2,097,152)
// ws layout (bytes):  total ~4.8 MB
#define IVN_OFF  0                            // 64 f32: 1/frobenius-norm [ten][j]
#define ICN_OFF  256                          // 2*8192 f32: 1/col-norm [ten][j][s]
#define CSQ_OFF  (ICN_OFF + 65536)            // 8 tc-partials x 2*8192 f32 = 512 KB
#define MATS_OFF (CSQ_OFF + 524288)           // 2 fp8 images (Vq, Aq), swizzled, 4 MB

typedef float f32x4 __attribute__((ext_vector_type(4)));
typedef int   i32x4 __attribute__((ext_vector_type(4)));
typedef int   i32x8 __attribute__((ext_vector_type(8)));   // 32 fp8 = one MX MFMA operand

// Image layout (R11-verbatim): plain k-order rows (256 B per image row r), 16B
// chunk c (k in [c*16, c*16+16)) stored at 16B slot c ^ (r & 15). XOR swizzle
// was for conflict-free ds_read; harmless for the global-gather path (the
// wave still gathers a contiguous L1-hot 4KB region per tile).
__global__ void cast_ns_k(const float* __restrict__ V, const float* __restrict__ A,
                          unsigned char* __restrict__ mats, float* __restrict__ csq){
  const int tc = blockIdx.x, j = blockIdx.y, ten = blockIdx.z;
  const int tid = threadIdx.x;
  const int g    = tid & 31;                 // d-chunk of 8 floats = 8 fp8 bytes
  const int tsub = tid >> 5;                 // 0..7
  const int c    = g >> 1;                   // 16B chunk index 0..15
  const int half = g & 1;                    // which 8B half of the chunk
  const float* X = (ten ? A : V) + (size_t)j * 65536;
  unsigned char* M = mats + (size_t)ten * SLOT + (size_t)j * 65536;
  float cs[8];
  #pragma unroll
  for (int e = 0; e < 8; ++e) cs[e] = 0.f;
  #pragma unroll
  for (int tt = 0; tt < 4; ++tt){
    const int t = tc * 32 + tt * 8 + tsub;
    const float4 p0 = *(const float4*)(X + t * 256 + g * 8);
    const float4 p1 = *(const float4*)(X + t * 256 + g * 8 + 4);
    cs[0] += p0.x * p0.x; cs[1] += p0.y * p0.y; cs[2] += p0.z * p0.z; cs[3] += p0.w * p0.w;
    cs[4] += p1.x * p1.x; cs[5] += p1.y * p1.y; cs[6] += p1.z * p1.z; cs[7] += p1.w * p1.w;
    int d0 = __builtin_amdgcn_cvt_pk_fp8_f32(p0.x, p0.y, 0, false);
    d0     = __builtin_amdgcn_cvt_pk_fp8_f32(p0.z, p0.w, d0, true);
    int d1 = __builtin_amdgcn_cvt_pk_fp8_f32(p1.x, p1.y, 0, false);
    d1     = __builtin_amdgcn_cvt_pk_fp8_f32(p1.z, p1.w, d1, true);
    int2 o; o.x = d0; o.y = d1;
    *(int2*)(M + (size_t)t * 256 + (((c ^ (t & 15)) << 4) | (half << 3))) = o;
  }
  __shared__ float red[8][256];
  #pragma unroll
  for (int e = 0; e < 8; ++e) red[tsub][g * 8 + e] = cs[e];
  __syncthreads();
  float s = 0.f;
  #pragma unroll
  for (int gg = 0; gg < 8; ++gg) s += red[gg][tid];
  csq[(size_t)((tc * 2 + ten) * 32 + j) * 256 + tid] = s;
}

// Finish norms: sum 8 tc-partials; icn = rsqrt, ivn = rsqrt of row-sum. Grid (32, 2).
__global__ void nreduce_k(const float* __restrict__ csq, float* __restrict__ ivn,
                          float* __restrict__ icn){
  const int j = blockIdx.x, ten = blockIdx.y, s = threadIdx.x;
  float c = 0.f;
  #pragma unroll
  for (int tc = 0; tc < 8; ++tc)
    c += csq[(size_t)((tc * 2 + ten) * 32 + j) * 256 + s];
  icn[ten * 8192 + j * 256 + s] = rsqrtf(c + 1e-18f);
  __shared__ float red[256];
  red[s] = c; __syncthreads();
  for (int off = 128; off > 0; off >>= 1){
    if (s < off) red[s] += red[s + off];
    __syncthreads();
  }
  if (s == 0) ivn[ten * 32 + j] = rsqrtf(red[0] + 1e-18f);
}

// v18: NO LDS staging for B. v13-v17 all pace at ~870-940 cy/wave-step
// regardless of schedule; the invariant subsystem is the glds+ds_read LDS
// staging of L2-RESIDENT data (col images = 4MB, fit in one XCD's L2;
// 507 MB/dispatch of pure L2->LDS copy overhead -- Common-mistake #7).
// B-fragments now load straight from global into registers, double-buffered,
// issued 2 tiles (~2 steps) ahead: per instr the wave gathers 64x16B from a
// contiguous 4KB L1/L2-hot region. No glds, no ds_read_b128, no manual
// waitcnts -- the compiler inserts precise counted vmcnt itself (m97
// evidence; 4 rounds showed my inline-asm discipline adds nothing).
// WAR note: loads for x+2 are issued AFTER the MFMAs reading the same regs
// (program order) and ~200cy of EXPACC separates them; load writeback is
// 100s of cycles later -- safe.
// LDS now: csc table (8KB) + epilogue ebuf (18KB) = 26.6KB. Live regs ~154
// (S-dbuf dropped, DMA machinery gone) -> (256,3): 3 blocks/CU. If
// WRITE_SIZE jumps >20MB it spilled -> revert to (256,2).
__global__ __launch_bounds__(256, 3) void gemm_both_k(const unsigned char* __restrict__ mats,
                                                      const float* __restrict__ ivn,
                                                      const float* __restrict__ icn,
                                                      float* __restrict__ out){
  __shared__ __align__(16) char smem[26624];  // [0,18432): ebuf f32[2][64][36]; [18432,26624): csc
  const int tid  = threadIdx.x;
  const int lane = tid & 63;
  const int w    = tid >> 6;
  const int dir  = w >> 1;              // waves 0,1 -> dir0; 2,3 -> dir1
  const int wn   = (w & 1) * 16;        // wave col slice in 32-col block tile
  const int lm   = lane & 15;
  const int kh   = lane >> 4;           // 0..3 (k-quad: k in [kh*32, kh*32+32) per K-half)
  const int s0   = blockIdx.x * 32;
  const int rb   = blockIdx.y;
  const int r0   = rb * 64;
  const int ib   = rb >> 2;             // batch index of this row tile (excluded diagonal)

  // dir0: rows Vq (scale 1/|V_i|F), cols Aq (scale 1/colnorm A); dir1 swapped.
  const unsigned char* rowmat = mats + (size_t)dir * SLOT;
  const unsigned char* colmat = mats + (size_t)(1 - dir) * SLOT;
  const float sivn = ivn[dir * 32 + ib] * 1.44269504088896340736f;  // * log2(e)

  float* ebuf = (float*)smem;
  float* cscw = (float*)(smem + 18432) + w * 512;      // wave-private csc table
  const unsigned char* colbase = colmat + (size_t)(s0 + wn) * 256;

  // Per-wave csc table: csc[j][lm] = sivn * icn_col[j*256 + lm], all 32 j.
  {
    const float* ibase = icn + (size_t)(1 - dir) * 8192 + s0 + wn;
    #pragma unroll
    for (int jx = 0; jx < 8; ++jx){
      const int j = kh * 8 + jx;
      cscw[j * 16 + lm] = sivn * ibase[j * 256 + lm];
    }
  }

  // A-fragments: all 64 rows of this wave's dir; K-half t, 16B unit u at slot
  // (t*8 + kh*2 + u) ^ lm. 64 regs, loop-invariant.
  i32x8 afr[4][2];                      // [mi][K-half]
  #pragma unroll
  for (int mi = 0; mi < 4; ++mi){
    const unsigned char* rp = rowmat + (size_t)(r0 + mi * 16 + lm) * 256;
    #pragma unroll
    for (int t = 0; t < 2; ++t){
      i32x4 lo = *(const i32x4*)(rp + ((((t << 3) | (kh << 1) | 0) ^ lm) << 4));
      i32x4 hi = *(const i32x4*)(rp + ((((t << 3) | (kh << 1) | 1) ^ lm) << 4));
      afr[mi][t] = i32x8{lo.x, lo.y, lo.z, lo.w, hi.x, hi.y, hi.z, hi.w};
    }
  }
  #pragma unroll
  for (int mi = 0; mi < 4; ++mi)
    #pragma unroll
    for (int t = 0; t < 2; ++t)
      asm volatile("" : "+v"(afr[mi][t]));

  // Step-invariant per-lane gather offsets within a 4KB j-tile (same pattern
  // the ds_reads used): off[t][u] = lm*256 + ((t*8+kh*2+u)^lm)*16.
  int boff[2][2];
  #pragma unroll
  for (int t = 0; t < 2; ++t)
    #pragma unroll
    for (int u = 0; u < 2; ++u)
      boff[t][u] = lm * 256 + ((((t << 3) | (kh << 1) | u) ^ lm) << 4);

  f32x4 acc[4];
  #pragma unroll
  for (int mi = 0; mi < 4; ++mi)
    acc[mi] = f32x4{0.f, 0.f, 0.f, 0.f};
  const f32x4 fz = {0.f, 0.f, 0.f, 0.f};   // hoisted zero C-operand for MFMA t=0

  i32x8 bA[2], bB[2];                   // B fragments, double-buffered (named)
  f32x4 S[4];                           // single S buffer (TLP covers exp dep)
  float cscA, cscB;                     // csc rotation, parity-named

#define JOF(x_) ((x_) + ((x_) >= ib ? 1 : 0))

#define LOADB(BX, x_) do{                                                       \
    const unsigned char* p_ = colbase + (size_t)JOF(x_) * 65536;                \
    i32x4 lo0_ = *(const i32x4*)(p_ + boff[0][0]);                              \
    i32x4 hi0_ = *(const i32x4*)(p_ + boff[0][1]);                              \
    i32x4 lo1_ = *(const i32x4*)(p_ + boff[1][0]);                              \
    i32x4 hi1_ = *(const i32x4*)(p_ + boff[1][1]);                              \
    BX[0] = i32x8{lo0_.x, lo0_.y, lo0_.z, lo0_.w, hi0_.x, hi0_.y, hi0_.z, hi0_.w}; \
    BX[1] = i32x8{lo1_.x, lo1_.y, lo1_.z, lo1_.w, hi1_.x, hi1_.y, hi1_.z, hi1_.w}; \
  }while(0)

#define MFMA8(BX) do{                                                           \
    S[0] = __builtin_amdgcn_mfma_scale_f32_16x16x128_f8f6f4(afr[0][0], BX[0], fz,   0, 0, 0, 127, 0, 127); \
    S[1] = __builtin_amdgcn_mfma_scale_f32_16x16x128_f8f6f4(afr[1][0], BX[0], fz,   0, 0, 0, 127, 0, 127); \
    S[2] = __builtin_amdgcn_mfma_scale_f32_16x16x128_f8f6f4(afr[2][0], BX[0], fz,   0, 0, 0, 127, 0, 127); \
    S[3] = __builtin_amdgcn_mfma_scale_f32_16x16x128_f8f6f4(afr[3][0], BX[0], fz,   0, 0, 0, 127, 0, 127); \
    S[0] = __builtin_amdgcn_mfma_scale_f32_16x16x128_f8f6f4(afr[0][1], BX[1], S[0], 0, 0, 0, 127, 0, 127); \
    S[1] = __builtin_amdgcn_mfma_scale_f32_16x16x128_f8f6f4(afr[1][1], BX[1], S[1], 0, 0, 0, 127, 0, 127); \
    S[2] = __builtin_amdgcn_mfma_scale_f32_16x16x128_f8f6f4(afr[2][1], BX[1], S[2], 0, 0, 0, 127, 0, 127); \
    S[3] = __builtin_amdgcn_mfma_scale_f32_16x16x128_f8f6f4(afr[3][1], BX[1], S[3], 0, 0, 0, 127, 0, 127); \
  }while(0)

#define EXPACC(CY) do{                                                          \
    _Pragma("unroll")                                                           \
    for (int mi_ = 0; mi_ < 4; ++mi_){                                          \
      _Pragma("unroll")                                                         \
      for (int r_ = 0; r_ < 4; ++r_)                                            \
        acc[mi_][r_] += __builtin_amdgcn_exp2f(S[mi_][r_] * CY);                \
    }                                                                           \
  }while(0)

  // ---- prologue: b(0), b(1) in flight; csc(0) staged ----
  LOADB(bA, 0);
  LOADB(bB, 1);
  cscA = cscw[JOF(0) * 16 + lm];

  // ---- steady state: even x -> bA, odd x -> bB; prefetch x+2 into the
  // buffer the MFMAs just consumed; stage csc(x+1) into the other name. ----
  #pragma unroll 1
  for (int it = 0; it < 14; ++it){
    const int x0 = 2 * it;
    MFMA8(bA);
    cscB = cscw[JOF(x0 + 1) * 16 + lm];
    LOADB(bA, x0 + 2);
    EXPACC(cscA);
    MFMA8(bB);
    cscA = cscw[JOF(x0 + 2) * 16 + lm];
    LOADB(bB, x0 + 3);
    EXPACC(cscB);
  }
  // x = 28 (even): prefetch x+2 = 30 (last tile)
  MFMA8(bA);
  cscB = cscw[JOF(29) * 16 + lm];
  LOADB(bA, 30);
  EXPACC(cscA);
  // x = 29 (odd): no prefetch (31 doesn't exist)
  MFMA8(bB);
  cscA = cscw[JOF(30) * 16 + lm];
  EXPACC(cscB);
  // x = 30 (even, last)
  MFMA8(bA);
  EXPACC(cscA);

#undef EXPACC
#undef MFMA8
#undef LOADB
#undef JOF

  // Epilogue: per-dir log1p into LDS ([2][64][36] f32 = 18KB), combine, coalesced store.
  // C/D layout: col = lane&15, row = (lane>>4)*4 + reg (shape-determined, incl. f8f6f4).
  #pragma unroll
  for (int mi = 0; mi < 4; ++mi){
    const int n = wn + lm;
    #pragma unroll
    for (int r = 0; r < 4; ++r){
      const int m = mi * 16 + (kh << 2) + r;
      ebuf[(dir * 64 + m) * 36 + n] = __logf(1.f + acc[mi][r]);
    }
  }
  __syncthreads();
  #pragma unroll
  for (int p = 0; p < 2; ++p){
    const int i   = tid + p * 256;     // 0..511 (float4 units of the 64x32 tile)
    const int row = i >> 3;
    const int c4  = i & 7;
    const f32x4 e0 = *(const f32x4*)(&ebuf[row * 36 + c4 * 4]);
    const f32x4 e1 = *(const f32x4*)(&ebuf[(64 + row) * 36 + c4 * 4]);
    f32x4 o;
    #pragma unroll
    for (int e = 0; e < 4; ++e) o[e] = -(e0[e] + e1[e]);
    *(f32x4*)(&out[(size_t)(r0 + row) * 256 + s0 + c4 * 4]) = o;
  }
}

extern "C" void kernel_launch(void* const* d_in, const int* in_sizes, int n_in,
                              void* d_out, int out_size, void* d_ws, size_t ws_size,
                              hipStream_t stream){
  const float* V = (const float*)d_in[2];   // back_VF  (pre_VF/pre_AF unused by reference)
  const float* A = (const float*)d_in[3];   // back_AF
  float* out = (float*)d_out;
  float* ivn = (float*)((char*)d_ws + IVN_OFF);
  float* icn = (float*)((char*)d_ws + ICN_OFF);
  float* csq = (float*)((char*)d_ws + CSQ_OFF);
  unsigned char* mats = (unsigned char*)((char*)d_ws + MATS_OFF);

  cast_ns_k<<<dim3(8, 32, 2), 256, 0, stream>>>(V, A, mats, csq);
  nreduce_k<<<dim3(32, 2), 256, 0, stream>>>(csq, ivn, icn);
  gemm_both_k<<<dim3(8, 128), 256, 0, stream>>>(mats, ivn, icn, out);
}

// Round 6
// 120.345 us; speedup vs baseline: 1.0962x; 1.0962x over previous
//
#include <hip/hip_runtime.h>
#include <cstdint>

// Problem constants: B=32, T=D=256, rows R = B*T = 8192, K = 256.
#define R_TOT 8192
#define KD    256
#define SLOT  ((size_t)R_TOT * KD)            // bytes per fp8 image (2,097,152)
// ws layout (bytes):  total ~4.8 MB
#define IVN_OFF  0                            // 64 f32: 1/frobenius-norm [ten][j]
#define ICN_OFF  256                          // 2*8192 f32: 1/col-norm [ten][j][s]
#define CSQ_OFF  (ICN_OFF + 65536)            // 8 tc-partials x 2*8192 f32 = 512 KB
#define MATS_OFF (CSQ_OFF + 524288)           // 2 fp8 images (Vq, Aq), swizzled, 4 MB

typedef float f32x4 __attribute__((ext_vector_type(4)));
typedef int   i32x4 __attribute__((ext_vector_type(4)));
typedef int   i32x8 __attribute__((ext_vector_type(8)));   // 32 fp8 = one MX MFMA operand

__device__ __forceinline__ void glds16(const void* g, void* l){
  __builtin_amdgcn_global_load_lds((const __attribute__((address_space(1))) uint32_t*)g,
                                   (__attribute__((address_space(3))) uint32_t*)l, 16, 0, 0);
}

// Image layout (R11-verbatim): plain k-order rows (256 B per image row r), 16B
// chunk c (k in [c*16, c*16+16)) stored at 16B slot c ^ (r & 15). XOR swizzle
// keeps MFMA-layout ds_read_b128 conflict-free (verified R7-R11).
__global__ void cast_ns_k(const float* __restrict__ V, const float* __restrict__ A,
                          unsigned char* __restrict__ mats, float* __restrict__ csq){
  const int tc = blockIdx.x, j = blockIdx.y, ten = blockIdx.z;
  const int tid = threadIdx.x;
  const int g    = tid & 31;                 // d-chunk of 8 floats = 8 fp8 bytes
  const int tsub = tid >> 5;                 // 0..7
  const int c    = g >> 1;                   // 16B chunk index 0..15
  const int half = g & 1;                    // which 8B half of the chunk
  const float* X = (ten ? A : V) + (size_t)j * 65536;
  unsigned char* M = mats + (size_t)ten * SLOT + (size_t)j * 65536;
  float cs[8];
  #pragma unroll
  for (int e = 0; e < 8; ++e) cs[e] = 0.f;
  #pragma unroll
  for (int tt = 0; tt < 4; ++tt){
    const int t = tc * 32 + tt * 8 + tsub;
    const float4 p0 = *(const float4*)(X + t * 256 + g * 8);
    const float4 p1 = *(const float4*)(X + t * 256 + g * 8 + 4);
    cs[0] += p0.x * p0.x; cs[1] += p0.y * p0.y; cs[2] += p0.z * p0.z; cs[3] += p0.w * p0.w;
    cs[4] += p1.x * p1.x; cs[5] += p1.y * p1.y; cs[6] += p1.z * p1.z; cs[7] += p1.w * p1.w;
    int d0 = __builtin_amdgcn_cvt_pk_fp8_f32(p0.x, p0.y, 0, false);
    d0     = __builtin_amdgcn_cvt_pk_fp8_f32(p0.z, p0.w, d0, true);
    int d1 = __builtin_amdgcn_cvt_pk_fp8_f32(p1.x, p1.y, 0, false);
    d1     = __builtin_amdgcn_cvt_pk_fp8_f32(p1.z, p1.w, d1, true);
    int2 o; o.x = d0; o.y = d1;
    *(int2*)(M + (size_t)t * 256 + (((c ^ (t & 15)) << 4) | (half << 3))) = o;
  }
  __shared__ float red[8][256];
  #pragma unroll
  for (int e = 0; e < 8; ++e) red[tsub][g * 8 + e] = cs[e];
  __syncthreads();
  float s = 0.f;
  #pragma unroll
  for (int gg = 0; gg < 8; ++gg) s += red[gg][tid];
  csq[(size_t)((tc * 2 + ten) * 32 + j) * 256 + tid] = s;
}

// Finish norms: sum 8 tc-partials; icn = rsqrt, ivn = rsqrt of row-sum. Grid (32, 2).
__global__ void nreduce_k(const float* __restrict__ csq, float* __restrict__ ivn,
                          float* __restrict__ icn){
  const int j = blockIdx.x, ten = blockIdx.y, s = threadIdx.x;
  float c = 0.f;
  #pragma unroll
  for (int tc = 0; tc < 8; ++tc)
    c += csq[(size_t)((tc * 2 + ten) * 32 + j) * 256 + s];
  icn[ten * 8192 + j * 256 + s] = rsqrtf(c + 1e-18f);
  __shared__ float red[256];
  red[s] = c; __syncthreads();
  for (int off = 128; off > 0; off >>= 1){
    if (s < off) red[s] += red[s + off];
    __syncthreads();
  }
  if (s == 0) ivn[ten * 32 + j] = rsqrtf(red[0] + 1e-18f);
}

// v19: 2x per-wave tile (64 rows x 32 cols/step, 16 MFMA) to amortize the
// per-step fixed overhead that v13-v17 showed is schedule-invariant
// (~870-940 cy/wave-step vs ~276 MFMA-cy of real work). v18 showed direct
// global gather is worse (scattered 16B gather = 32 cachelines/instr), so
// glds->LDS->ds_read_b128 staging is restored. Sync discipline = v13's
// proven minimum: manual vmcnt for the glds->ds_read hazard (compiler does
// NOT track DMA->LDS deps), compiler-managed lgkm for ds_read->MFMA, no
// setprio (m190), no sched_barriers. Block = 128 rows x 32 cols, 4 waves
// (2 dirs x 2 row-halves), grid 8x64 = 512 = exactly 2 blocks/CU resident.
// Regs ~195 (afr 64 + b 32 + S 32 + acc 32 + misc) -> (256,2), no spill.
// LDS 80KB: 4 waves x 2-phase x 8KB staging + 4 x 4KB csc; epilogue ebuf
// (36.9KB) aliases the staging region after syncthreads.
__global__ __launch_bounds__(256, 2) void gemm_both_k(const unsigned char* __restrict__ mats,
                                                      const float* __restrict__ ivn,
                                                      const float* __restrict__ icn,
                                                      float* __restrict__ out){
  __shared__ __align__(16) char smem[81920];
  const int tid  = threadIdx.x;
  const int lane = tid & 63;
  const int w    = tid >> 6;
  const int dir  = w >> 1;              // waves 0,1 -> dir0; 2,3 -> dir1
  const int half = w & 1;               // which 64-row half of the 128-row block
  const int lm   = lane & 15;
  const int kh   = lane >> 4;           // 0..3 (k-quad per K-half)
  const int s0   = blockIdx.x * 32;
  const int rb   = blockIdx.y;
  const int r0   = rb * 128;
  const int ib   = rb >> 1;             // batch index of this row tile (excluded diagonal)

  // dir0: rows Vq (scale 1/|V_i|F), cols Aq (scale 1/colnorm A); dir1 swapped.
  const unsigned char* rowmat = mats + (size_t)dir * SLOT;
  const unsigned char* colmat = mats + (size_t)(1 - dir) * SLOT;
  const float sivn = ivn[dir * 32 + ib] * 1.44269504088896340736f;  // * log2(e)

  char* wbase = smem + w * 16384;                      // wave-private 2-phase x 8KB
  float* cscw = (float*)(smem + 65536) + w * 1024;     // wave-private csc[32j][32col]
  const int lo16 = lane * 16;
  const unsigned char* colbase = colmat + (size_t)s0 * 256;   // 8KB j-tile @ +j*65536

  // glds DMA batch for column-tile index x (x in [0,31), j = x + (x>=ib)).
  auto issue = [&](int x){
    const int j = x + (x >= ib ? 1 : 0);
    const unsigned char* src = colbase + (size_t)j * 65536;
    char* dst = wbase + ((x & 1) << 13);
    #pragma unroll
    for (int c = 0; c < 8; ++c)
      glds16(src + c * 1024 + lo16, dst + c * 1024 + lo16);
  };

  issue(0);   // start DMA of x=0 before anything else

  // Per-wave csc table: csc[j][col] = sivn * icn_col[j*256 + s0 + col].
  {
    const int col = lane & 31;
    const float* ib2 = icn + (size_t)(1 - dir) * 8192 + s0 + col;
    #pragma unroll
    for (int jx = 0; jx < 16; ++jx){
      const int j = jx * 2 + (lane >> 5);
      cscw[j * 32 + col] = sivn * ib2[j * 256];
    }
  }

  // A-fragments: 64 rows (this wave's half); K-half t, 16B unit u at slot
  // (t*8 + kh*2 + u) ^ lm. 64 regs, loop-invariant.
  i32x8 afr[4][2];                      // [mi][K-half]
  #pragma unroll
  for (int mi = 0; mi < 4; ++mi){
    const unsigned char* rp = rowmat + (size_t)(r0 + half * 64 + mi * 16 + lm) * 256;
    #pragma unroll
    for (int t = 0; t < 2; ++t){
      i32x4 lo = *(const i32x4*)(rp + ((((t << 3) | (kh << 1) | 0) ^ lm) << 4));
      i32x4 hi = *(const i32x4*)(rp + ((((t << 3) | (kh << 1) | 1) ^ lm) << 4));
      afr[mi][t] = i32x8{lo.x, lo.y, lo.z, lo.w, hi.x, hi.y, hi.z, hi.w};
    }
  }
  #pragma unroll
  for (int mi = 0; mi < 4; ++mi)
    #pragma unroll
    for (int t = 0; t < 2; ++t)
      asm volatile("" : "+v"(afr[mi][t]));

  // ds_read offsets: col-group nj (rows nj*16+lm of the 8KB tile), K-half t,
  // unit u. Image row = s0+nj*16+lm -> (r&15)==lm, same XOR as staging.
  int ad[2][2][2];                      // [nj][K-half][unit]
  #pragma unroll
  for (int nj = 0; nj < 2; ++nj)
    #pragma unroll
    for (int t = 0; t < 2; ++t)
      #pragma unroll
      for (int u = 0; u < 2; ++u)
        ad[nj][t][u] = (nj * 16 + lm) * 256 + ((((t << 3) | (kh << 1) | u) ^ lm) << 4);

  f32x4 acc[4][2];
  #pragma unroll
  for (int mi = 0; mi < 4; ++mi)
    #pragma unroll
    for (int nj = 0; nj < 2; ++nj)
      acc[mi][nj] = f32x4{0.f, 0.f, 0.f, 0.f};
  const f32x4 fz = {0.f, 0.f, 0.f, 0.f};   // hoisted zero C-operand for MFMA t=0

  // Pre-loop: drain preload DMA + csc global loads + afr + csc LDS writes.
  asm volatile("s_waitcnt vmcnt(0) lgkmcnt(0)" ::: "memory");

  #pragma unroll 1
  for (int jj = 0; jj < 31; ++jj){
    const int j = jj + (jj >= ib ? 1 : 0);

    // Prefetch jj+1 FIRST, then vmcnt(8): waits only for the PREVIOUS
    // iteration's 8 glds (aged ~1 step); the 8 just issued stay in flight.
    if (jj < 30){
      issue(jj + 1);
      asm volatile("s_waitcnt vmcnt(8)" ::: "memory");
    } else {
      asm volatile("s_waitcnt vmcnt(0)" ::: "memory");
    }

    const char* rbuf = wbase + ((jj & 1) << 13);
    i32x8 b[2][2];                      // [K-half][nj]
    #pragma unroll
    for (int nj = 0; nj < 2; ++nj)
      #pragma unroll
      for (int t = 0; t < 2; ++t){
        i32x4 lo = *(const i32x4*)(rbuf + ad[nj][t][0]);
        i32x4 hi = *(const i32x4*)(rbuf + ad[nj][t][1]);
        b[t][nj] = i32x8{lo.x, lo.y, lo.z, lo.w, hi.x, hi.y, hi.z, hi.w};
      }
    const float csc0 = cscw[j * 32 + lm];
    const float csc1 = cscw[j * 32 + 16 + lm];

    f32x4 S[4][2];
    #pragma unroll
    for (int mi = 0; mi < 4; ++mi){
      S[mi][0] = __builtin_amdgcn_mfma_scale_f32_16x16x128_f8f6f4(afr[mi][0], b[0][0], fz, 0, 0, 0, 127, 0, 127);
      S[mi][1] = __builtin_amdgcn_mfma_scale_f32_16x16x128_f8f6f4(afr[mi][0], b[0][1], fz, 0, 0, 0, 127, 0, 127);
    }
    #pragma unroll
    for (int mi = 0; mi < 4; ++mi){
      S[mi][0] = __builtin_amdgcn_mfma_scale_f32_16x16x128_f8f6f4(afr[mi][1], b[1][0], S[mi][0], 0, 0, 0, 127, 0, 127);
      S[mi][1] = __builtin_amdgcn_mfma_scale_f32_16x16x128_f8f6f4(afr[mi][1], b[1][1], S[mi][1], 0, 0, 0, 127, 0, 127);
    }

    #pragma unroll
    for (int mi = 0; mi < 4; ++mi){
      const f32x4 t0 = S[mi][0] * csc0;       // vector*scalar -> pk-able muls
      const f32x4 t1 = S[mi][1] * csc1;
      f32x4 e0, e1;
      #pragma unroll
      for (int r = 0; r < 4; ++r){ e0[r] = __builtin_amdgcn_exp2f(t0[r]); e1[r] = __builtin_amdgcn_exp2f(t1[r]); }
      acc[mi][0] += e0;                       // pk-able adds
      acc[mi][1] += e1;
    }
  }

  // Epilogue: per-dir log1p into LDS (f32[2][128][36] = 36.9KB, aliases the
  // staging region -- safe after syncthreads), combine dirs, coalesced store.
  // C/D layout: col = lane&15, row = (lane>>4)*4 + reg (shape-determined).
  __syncthreads();
  float* ebuf = (float*)smem;
  #pragma unroll
  for (int mi = 0; mi < 4; ++mi){
    #pragma unroll
    for (int nj = 0; nj < 2; ++nj){
      const int n = nj * 16 + lm;
      #pragma unroll
      for (int r = 0; r < 4; ++r){
        const int m = half * 64 + mi * 16 + (kh << 2) + r;
        ebuf[(dir * 128 + m) * 36 + n] = __logf(1.f + acc[mi][nj][r]);
      }
    }
  }
  __syncthreads();
  #pragma unroll
  for (int p = 0; p < 4; ++p){
    const int i   = tid + p * 256;     // 0..1023 (float4 units of the 128x32 tile)
    const int row = i >> 3;
    const int c4  = i & 7;
    const f32x4 e0 = *(const f32x4*)(&ebuf[row * 36 + c4 * 4]);
    const f32x4 e1 = *(const f32x4*)(&ebuf[(128 + row) * 36 + c4 * 4]);
    f32x4 o;
    #pragma unroll
    for (int e = 0; e < 4; ++e) o[e] = -(e0[e] + e1[e]);
    *(f32x4*)(&out[(size_t)(r0 + row) * 256 + s0 + c4 * 4]) = o;
  }
}

extern "C" void kernel_launch(void* const* d_in, const int* in_sizes, int n_in,
                              void* d_out, int out_size, void* d_ws, size_t ws_size,
                              hipStream_t stream){
  const float* V = (const float*)d_in[2];   // back_VF  (pre_VF/pre_AF unused by reference)
  const float* A = (const float*)d_in[3];   // back_AF
  float* out = (float*)d_out;
  float* ivn = (float*)((char*)d_ws + IVN_OFF);
  float* icn = (float*)((char*)d_ws + ICN_OFF);
  float* csq = (float*)((char*)d_ws + CSQ_OFF);
  unsigned char* mats = (unsigned char*)((char*)d_ws + MATS_OFF);

  cast_ns_k<<<dim3(8, 32, 2), 256, 0, stream>>>(V, A, mats, csq);
  nreduce_k<<<dim3(32, 2), 256, 0, stream>>>(csq, ivn, icn);
  gemm_both_k<<<dim3(8, 64), 256, 0, stream>>>(mats, ivn, icn, out);
}

// Round 7
// 119.230 us; speedup vs baseline: 1.1064x; 1.0093x over previous
//
#include <hip/hip_runtime.h>
#include <cstdint>

// Problem constants: B=32, T=D=256, rows R = B*T = 8192, K = 256.
#define R_TOT 8192
#define KD    256
#define SLOT  ((size_t)R_TOT * KD)            // bytes per fp8 image (2,097,152)
// ws layout (bytes):  total ~4.8 MB
#define IVN_OFF  0                            // 64 f32: 1/frobenius-norm [ten][j]
#define ICN_OFF  256                          // 2*8192 f32: 1/col-norm [ten][j][s]
#define CSQ_OFF  (ICN_OFF + 65536)            // 8 tc-partials x 2*8192 f32 = 512 KB
#define MATS_OFF (CSQ_OFF + 524288)           // 2 fp8 images (Vq, Aq), swizzled, 4 MB

typedef float f32x4 __attribute__((ext_vector_type(4)));
typedef int   i32x4 __attribute__((ext_vector_type(4)));
typedef int   i32x8 __attribute__((ext_vector_type(8)));   // 32 fp8 = one MX MFMA operand

__device__ __forceinline__ void glds16(const void* g, void* l){
  __builtin_amdgcn_global_load_lds((const __attribute__((address_space(1))) uint32_t*)g,
                                   (__attribute__((address_space(3))) uint32_t*)l, 16, 0, 0);
}

// Image layout (R11-verbatim): plain k-order rows (256 B per image row r), 16B
// chunk c (k in [c*16, c*16+16)) stored at 16B slot c ^ (r & 15). XOR swizzle
// keeps MFMA-layout ds_read_b128 conflict-free (verified R7-R11).
__global__ void cast_ns_k(const float* __restrict__ V, const float* __restrict__ A,
                          unsigned char* __restrict__ mats, float* __restrict__ csq){
  const int tc = blockIdx.x, j = blockIdx.y, ten = blockIdx.z;
  const int tid = threadIdx.x;
  const int g    = tid & 31;                 // d-chunk of 8 floats = 8 fp8 bytes
  const int tsub = tid >> 5;                 // 0..7
  const int c    = g >> 1;                   // 16B chunk index 0..15
  const int half = g & 1;                    // which 8B half of the chunk
  const float* X = (ten ? A : V) + (size_t)j * 65536;
  unsigned char* M = mats + (size_t)ten * SLOT + (size_t)j * 65536;
  float cs[8];
  #pragma unroll
  for (int e = 0; e < 8; ++e) cs[e] = 0.f;
  #pragma unroll
  for (int tt = 0; tt < 4; ++tt){
    const int t = tc * 32 + tt * 8 + tsub;
    const float4 p0 = *(const float4*)(X + t * 256 + g * 8);
    const float4 p1 = *(const float4*)(X + t * 256 + g * 8 + 4);
    cs[0] += p0.x * p0.x; cs[1] += p0.y * p0.y; cs[2] += p0.z * p0.z; cs[3] += p0.w * p0.w;
    cs[4] += p1.x * p1.x; cs[5] += p1.y * p1.y; cs[6] += p1.z * p1.z; cs[7] += p1.w * p1.w;
    int d0 = __builtin_amdgcn_cvt_pk_fp8_f32(p0.x, p0.y, 0, false);
    d0     = __builtin_amdgcn_cvt_pk_fp8_f32(p0.z, p0.w, d0, true);
    int d1 = __builtin_amdgcn_cvt_pk_fp8_f32(p1.x, p1.y, 0, false);
    d1     = __builtin_amdgcn_cvt_pk_fp8_f32(p1.z, p1.w, d1, true);
    int2 o; o.x = d0; o.y = d1;
    *(int2*)(M + (size_t)t * 256 + (((c ^ (t & 15)) << 4) | (half << 3))) = o;
  }
  __shared__ float red[8][256];
  #pragma unroll
  for (int e = 0; e < 8; ++e) red[tsub][g * 8 + e] = cs[e];
  __syncthreads();
  float s = 0.f;
  #pragma unroll
  for (int gg = 0; gg < 8; ++gg) s += red[gg][tid];
  csq[(size_t)((tc * 2 + ten) * 32 + j) * 256 + tid] = s;
}

// Finish norms: sum 8 tc-partials; icn = rsqrt, ivn = rsqrt of row-sum. Grid (32, 2).
__global__ void nreduce_k(const float* __restrict__ csq, float* __restrict__ ivn,
                          float* __restrict__ icn){
  const int j = blockIdx.x, ten = blockIdx.y, s = threadIdx.x;
  float c = 0.f;
  #pragma unroll
  for (int tc = 0; tc < 8; ++tc)
    c += csq[(size_t)((tc * 2 + ten) * 32 + j) * 256 + s];
  icn[ten * 8192 + j * 256 + s] = rsqrtf(c + 1e-18f);
  __shared__ float red[256];
  red[s] = c; __syncthreads();
  for (int off = 128; off > 0; off >>= 1){
    if (s < off) red[s] += red[s + off];
    __syncthreads();
  }
  if (s == 0) ivn[ten * 32 + j] = rsqrtf(red[0] + 1e-18f);
}

// v20: STAGING-BANDWIDTH fix. v13/v16/v17/v19 all run the glds path at a
// constant 10-11 TB/s (m97=13, m201=12 on the same path) -> the kernel was
// staging-BW-bound the whole time (508 MB/dispatch, 127x redundant: unique
// col data is 4 MB). Fix: block-shared column tiles. Block = 512 threads
// (8 waves) = 256 rows (EXACTLY one batch i -> uniform diagonal skip and
// sivn) x 32 cols x both dirs. Per step the block stages 2 dirs x 8 KB
// (each wave issues 2 glds16 into its dir's shared 4-deep buffer); all 4
// same-dir waves read the same tile. Staged bytes: 256 blocks x 31 x 16 KB
// = 127 MB (4x cut) ~ 12 us at the path ceiling < 14.3 us MFMA floor ->
// MFMA-bound. Depth-2 prefetch (issue x+2), counted vmcnt(2) (the ONLY
// vmcnt ops in the loop are our 2 glds/step -> count is exact), raw
// s_barrier per step (NOT __syncthreads: that drains vmcnt to 0 = the m97
// stall). Grid 8x32 = 256 blocks = 1/CU. Regs ~180 live -> (512,2) cap 256.
__global__ __launch_bounds__(512, 2) void gemm_both_k(const unsigned char* __restrict__ mats,
                                                      const float* __restrict__ ivn,
                                                      const float* __restrict__ icn,
                                                      float* __restrict__ out){
  // [0,64K): 2 dirs x 4 bufs x 8KB staging; [64K,72K): csc[2][32][32] f32.
  // Epilogue ebuf f32[2][256][36] = 73728 B aliases everything (post-loop).
  __shared__ __align__(16) char smem[73728];
  const int tid  = threadIdx.x;
  const int lane = tid & 63;
  const int w    = tid >> 6;            // 0..7
  const int dir  = w >> 2;              // waves 0-3 -> dir0; 4-7 -> dir1
  const int q    = w & 3;               // row-quarter AND staging-chunk index
  const int lm   = lane & 15;
  const int kh   = lane >> 4;           // 0..3 (k-quad per K-half)
  const int s0   = blockIdx.x * 32;
  const int rb   = blockIdx.y;          // row-block == batch index i
  const int r0   = rb * 256;
  const int ib   = rb;                  // excluded diagonal j == i

  // dir0: rows Vq (scale 1/|V_i|F), cols Aq (scale 1/colnorm A); dir1 swapped.
  const unsigned char* rowmat = mats + (size_t)dir * SLOT;
  const unsigned char* colmat = mats + (size_t)(1 - dir) * SLOT;
  const float sivn = ivn[dir * 32 + ib] * 1.44269504088896340736f;  // * log2(e)

  char*  dbase = smem + dir * 32768;                  // this dir's 4 x 8KB bufs
  float* cscw  = (float*)(smem + 65536) + dir * 1024; // this dir's csc[32][32]
  const unsigned char* colbase = colmat + (size_t)s0 * 256;  // 8KB j-tile @ +j*65536
  const int lo16 = lane * 16;

  // Stage 2KB (this wave's quarter) of the dir's 8KB tile for col-tile x.
  auto issue = [&](int x){
    const int j = x + (x >= ib ? 1 : 0);
    const unsigned char* src = colbase + (size_t)j * 65536 + q * 2048;
    char* dst = dbase + ((x & 3) << 13) + q * 2048;
    glds16(src + lo16,        dst + lo16);
    glds16(src + 1024 + lo16, dst + 1024 + lo16);
  };

  issue(0);
  issue(1);

  // Block-shared csc table (per dir): csc[j][col] = sivn * icn_col[j*256+s0+col].
  // 4 waves x 64 lanes: each wave fills 8 j-rows (2 per iteration).
  {
    const int col = lane & 31;
    const int jh  = lane >> 5;          // 0/1
    const float* ib2 = icn + (size_t)(1 - dir) * 8192 + s0 + col;
    #pragma unroll
    for (int jx = 0; jx < 4; ++jx){
      const int j = q * 8 + jx * 2 + jh;
      cscw[j * 32 + col] = sivn * ib2[j * 256];
    }
  }

  // A-fragments: this wave's 64 rows (quarter q of the 256-row block);
  // K-half t, 16B unit u at slot (t*8 + kh*2 + u) ^ lm. 64 regs, invariant.
  i32x8 afr[4][2];                      // [mi][K-half]
  #pragma unroll
  for (int mi = 0; mi < 4; ++mi){
    const unsigned char* rp = rowmat + (size_t)(r0 + q * 64 + mi * 16 + lm) * 256;
    #pragma unroll
    for (int t = 0; t < 2; ++t){
      i32x4 lo = *(const i32x4*)(rp + ((((t << 3) | (kh << 1) | 0) ^ lm) << 4));
      i32x4 hi = *(const i32x4*)(rp + ((((t << 3) | (kh << 1) | 1) ^ lm) << 4));
      afr[mi][t] = i32x8{lo.x, lo.y, lo.z, lo.w, hi.x, hi.y, hi.z, hi.w};
    }
  }
  #pragma unroll
  for (int mi = 0; mi < 4; ++mi)
    #pragma unroll
    for (int t = 0; t < 2; ++t)
      asm volatile("" : "+v"(afr[mi][t]));

  // ds_read offsets: col-group nj -> tile row nj*16+lm ((row&15)==lm, same
  // XOR key as staging since s0 is a multiple of 32).
  int ad[2][2][2];                      // [nj][K-half][unit]
  #pragma unroll
  for (int nj = 0; nj < 2; ++nj)
    #pragma unroll
    for (int t = 0; t < 2; ++t)
      #pragma unroll
      for (int u = 0; u < 2; ++u)
        ad[nj][t][u] = (nj * 16 + lm) * 256 + ((((t << 3) | (kh << 1) | u) ^ lm) << 4);

  f32x4 acc[4][2];
  #pragma unroll
  for (int mi = 0; mi < 4; ++mi)
    #pragma unroll
    for (int nj = 0; nj < 2; ++nj)
      acc[mi][nj] = f32x4{0.f, 0.f, 0.f, 0.f};
  const f32x4 fz = {0.f, 0.f, 0.f, 0.f};   // hoisted zero C-operand for MFMA t=0

  // Drain prologue: csc gloads + afr loads + DMA(0),DMA(1) + csc LDS writes.
  asm volatile("s_waitcnt vmcnt(0) lgkmcnt(0)" ::: "memory");
  __builtin_amdgcn_s_barrier();
  __builtin_amdgcn_sched_barrier(0);

  #pragma unroll 1
  for (int x = 0; x < 31; ++x){
    const int j = x + (x >= ib ? 1 : 0);

    if (x <= 28) issue(x + 2);          // depth-2 prefetch into buf[(x+2)&3]

    const char* rbuf = dbase + ((x & 3) << 13);
    i32x8 b[2][2];                      // [K-half][nj]
    #pragma unroll
    for (int nj = 0; nj < 2; ++nj)
      #pragma unroll
      for (int t = 0; t < 2; ++t){
        i32x4 lo = *(const i32x4*)(rbuf + ad[nj][t][0]);
        i32x4 hi = *(const i32x4*)(rbuf + ad[nj][t][1]);
        b[t][nj] = i32x8{lo.x, lo.y, lo.z, lo.w, hi.x, hi.y, hi.z, hi.w};
      }
    const float csc0 = cscw[j * 32 + lm];
    const float csc1 = cscw[j * 32 + 16 + lm];

    f32x4 S[4][2];
    #pragma unroll
    for (int mi = 0; mi < 4; ++mi){
      S[mi][0] = __builtin_amdgcn_mfma_scale_f32_16x16x128_f8f6f4(afr[mi][0], b[0][0], fz, 0, 0, 0, 127, 0, 127);
      S[mi][1] = __builtin_amdgcn_mfma_scale_f32_16x16x128_f8f6f4(afr[mi][0], b[0][1], fz, 0, 0, 0, 127, 0, 127);
    }
    #pragma unroll
    for (int mi = 0; mi < 4; ++mi){
      S[mi][0] = __builtin_amdgcn_mfma_scale_f32_16x16x128_f8f6f4(afr[mi][1], b[1][0], S[mi][0], 0, 0, 0, 127, 0, 127);
      S[mi][1] = __builtin_amdgcn_mfma_scale_f32_16x16x128_f8f6f4(afr[mi][1], b[1][1], S[mi][1], 0, 0, 0, 127, 0, 127);
    }

    #pragma unroll
    for (int mi = 0; mi < 4; ++mi){
      const f32x4 t0 = S[mi][0] * csc0;
      const f32x4 t1 = S[mi][1] * csc1;
      f32x4 e0, e1;
      #pragma unroll
      for (int r = 0; r < 4; ++r){ e0[r] = __builtin_amdgcn_exp2f(t0[r]); e1[r] = __builtin_amdgcn_exp2f(t1[r]); }
      acc[mi][0] += e0;
      acc[mi][1] += e1;
    }

    // End-of-step sync: wait for DMA(x+1) (the pair issued LAST step; the 2
    // just issued for x+2 may stay in flight), then raw barrier so all 8
    // waves' contributions are visible. NOT __syncthreads (vmcnt(0) drain).
    if (x <= 28)      asm volatile("s_waitcnt vmcnt(2)" ::: "memory");
    else if (x == 29) asm volatile("s_waitcnt vmcnt(0)" ::: "memory");
    if (x < 30){
      __builtin_amdgcn_s_barrier();
      __builtin_amdgcn_sched_barrier(0);
    }
  }

  // Epilogue: per-dir log1p into LDS (aliases staging region -- dead after
  // this barrier), combine dirs, coalesced store.
  // C/D layout: col = lane&15, row = (lane>>4)*4 + reg (shape-determined).
  __syncthreads();
  float* ebuf = (float*)smem;
  #pragma unroll
  for (int mi = 0; mi < 4; ++mi){
    #pragma unroll
    for (int nj = 0; nj < 2; ++nj){
      const int n = nj * 16 + lm;
      #pragma unroll
      for (int r = 0; r < 4; ++r){
        const int m = q * 64 + mi * 16 + (kh << 2) + r;
        ebuf[(dir * 256 + m) * 36 + n] = __logf(1.f + acc[mi][nj][r]);
      }
    }
  }
  __syncthreads();
  #pragma unroll
  for (int p = 0; p < 4; ++p){
    const int i   = tid + p * 512;     // 0..2047 (float4 units of the 256x32 tile)
    const int row = i >> 3;
    const int c4  = i & 7;
    const f32x4 e0 = *(const f32x4*)(&ebuf[row * 36 + c4 * 4]);
    const f32x4 e1 = *(const f32x4*)(&ebuf[(256 + row) * 36 + c4 * 4]);
    f32x4 o;
    #pragma unroll
    for (int e = 0; e < 4; ++e) o[e] = -(e0[e] + e1[e]);
    *(f32x4*)(&out[(size_t)(r0 + row) * 256 + s0 + c4 * 4]) = o;
  }
}

extern "C" void kernel_launch(void* const* d_in, const int* in_sizes, int n_in,
                              void* d_out, int out_size, void* d_ws, size_t ws_size,
                              hipStream_t stream){
  const float* V = (const float*)d_in[2];   // back_VF  (pre_VF/pre_AF unused by reference)
  const float* A = (const float*)d_in[3];   // back_AF
  float* out = (float*)d_out;
  float* ivn = (float*)((char*)d_ws + IVN_OFF);
  float* icn = (float*)((char*)d_ws + ICN_OFF);
  float* csq = (float*)((char*)d_ws + CSQ_OFF);
  unsigned char* mats = (unsigned char*)((char*)d_ws + MATS_OFF);

  cast_ns_k<<<dim3(8, 32, 2), 256, 0, stream>>>(V, A, mats, csq);
  nreduce_k<<<dim3(32, 2), 256, 0, stream>>>(csq, ivn, icn);
  gemm_both_k<<<dim3(8, 32), 512, 0, stream>>>(mats, ivn, icn, out);
}

// Round 8
// 116.212 us; speedup vs baseline: 1.1352x; 1.0260x over previous
//
#include <hip/hip_runtime.h>
#include <cstdint>

// Problem constants: B=32, T=D=256, rows R = B*T = 8192, K = 256.
#define R_TOT 8192
#define KD    256
#define SLOT  ((size_t)R_TOT * KD)            // bytes per fp8 image (2,097,152)
// ws layout (bytes):  total ~4.8 MB
#define IVN_OFF  0                            // 64 f32: 1/frobenius-norm [ten][j]
#define ICN_OFF  256                          // 2*8192 f32: 1/col-norm [ten][j][s]
#define CSQ_OFF  (ICN_OFF + 65536)            // 8 tc-partials x 2*8192 f32 = 512 KB
#define MATS_OFF (CSQ_OFF + 524288)           // 2 fp8 images (Vq, Aq), swizzled, 4 MB

typedef float f32x4 __attribute__((ext_vector_type(4)));
typedef int   i32x4 __attribute__((ext_vector_type(4)));
typedef int   i32x8 __attribute__((ext_vector_type(8)));   // 32 fp8 = one MX MFMA operand

__device__ __forceinline__ void glds16(const void* g, void* l){
  __builtin_amdgcn_global_load_lds((const __attribute__((address_space(1))) uint32_t*)g,
                                   (__attribute__((address_space(3))) uint32_t*)l, 16, 0, 0);
}

// Image layout (R11-verbatim): plain k-order rows (256 B per image row r), 16B
// chunk c (k in [c*16, c*16+16)) stored at 16B slot c ^ (r & 15). XOR swizzle
// keeps MFMA-layout ds_read_b128 conflict-free (verified R7-R11).
__global__ void cast_ns_k(const float* __restrict__ V, const float* __restrict__ A,
                          unsigned char* __restrict__ mats, float* __restrict__ csq){
  const int tc = blockIdx.x, j = blockIdx.y, ten = blockIdx.z;
  const int tid = threadIdx.x;
  const int g    = tid & 31;                 // d-chunk of 8 floats = 8 fp8 bytes
  const int tsub = tid >> 5;                 // 0..7
  const int c    = g >> 1;                   // 16B chunk index 0..15
  const int half = g & 1;                    // which 8B half of the chunk
  const float* X = (ten ? A : V) + (size_t)j * 65536;
  unsigned char* M = mats + (size_t)ten * SLOT + (size_t)j * 65536;
  float cs[8];
  #pragma unroll
  for (int e = 0; e < 8; ++e) cs[e] = 0.f;
  #pragma unroll
  for (int tt = 0; tt < 4; ++tt){
    const int t = tc * 32 + tt * 8 + tsub;
    const float4 p0 = *(const float4*)(X + t * 256 + g * 8);
    const float4 p1 = *(const float4*)(X + t * 256 + g * 8 + 4);
    cs[0] += p0.x * p0.x; cs[1] += p0.y * p0.y; cs[2] += p0.z * p0.z; cs[3] += p0.w * p0.w;
    cs[4] += p1.x * p1.x; cs[5] += p1.y * p1.y; cs[6] += p1.z * p1.z; cs[7] += p1.w * p1.w;
    int d0 = __builtin_amdgcn_cvt_pk_fp8_f32(p0.x, p0.y, 0, false);
    d0     = __builtin_amdgcn_cvt_pk_fp8_f32(p0.z, p0.w, d0, true);
    int d1 = __builtin_amdgcn_cvt_pk_fp8_f32(p1.x, p1.y, 0, false);
    d1     = __builtin_amdgcn_cvt_pk_fp8_f32(p1.z, p1.w, d1, true);
    int2 o; o.x = d0; o.y = d1;
    *(int2*)(M + (size_t)t * 256 + (((c ^ (t & 15)) << 4) | (half << 3))) = o;
  }
  __shared__ float red[8][256];
  #pragma unroll
  for (int e = 0; e < 8; ++e) red[tsub][g * 8 + e] = cs[e];
  __syncthreads();
  float s = 0.f;
  #pragma unroll
  for (int gg = 0; gg < 8; ++gg) s += red[gg][tid];
  csq[(size_t)((tc * 2 + ten) * 32 + j) * 256 + tid] = s;
}

// Finish norms: sum 8 tc-partials; icn = rsqrt, ivn = rsqrt of row-sum. Grid (32, 2).
__global__ void nreduce_k(const float* __restrict__ csq, float* __restrict__ ivn,
                          float* __restrict__ icn){
  const int j = blockIdx.x, ten = blockIdx.y, s = threadIdx.x;
  float c = 0.f;
  #pragma unroll
  for (int tc = 0; tc < 8; ++tc)
    c += csq[(size_t)((tc * 2 + ten) * 32 + j) * 256 + s];
  icn[ten * 8192 + j * 256 + s] = rsqrtf(c + 1e-18f);
  __shared__ float red[256];
  red[s] = c; __syncthreads();
  for (int off = 128; off > 0; off >>= 1){
    if (s < off) red[s] += red[s + off];
    __syncthreads();
  }
  if (s == 0) ivn[ten * 32 + j] = rsqrtf(red[0] + 1e-18f);
}

// v21: TLP + shared staging, finally combined. Series reconciliation: v13
// (dur 44.8) compiled to 64 arch VGPR (+64 acc) = 128-reg waves -> 4
// waves/SIMD resident; every later variant traded TLP for ILP (156+ regs ->
// 2-3 waves/SIMD) or shrank the grid (v20: 1 block/CU = 2 waves/SIMD) and
// lost. Issue accounting: per-SIMD VALU ~21us busy + MFMA ~13us busy; only
// staggered TLP fills the gaps.
// v21 block = 1024 threads = 16 waves = 256 rows (one batch i -> uniform
// diagonal skip + sivn) x 32 cols x both dirs. Wave = 32 rows: afr 32 regs
// (vs v13's 64), b 32, S 16, acc 16 -> ~115 live, fits the 128-reg cap ->
// 16 waves/CU = 4/SIMD at 1 block/CU. Staged bytes = 256 blocks x 31 x
// 16KB = 127 MB (4x cut, ~11us of glds-path BW < 14.3us MFMA floor). Per
// step each wave issues exactly ONE glds16 (1KB of its dir's shared 8KB
// tile), 4-deep buffers, invariant-exact vmcnt(1) + raw s_barrier (never
// vmcnt(0) mid-loop; __syncthreads would drain it = m97 stall). Spill
// detector: WRITE_SIZE (8MB clean; ballooned = 128-reg fit failed).
__global__ __launch_bounds__(1024, 4) void gemm_both_k(const unsigned char* __restrict__ mats,
                                                       const float* __restrict__ ivn,
                                                       const float* __restrict__ icn,
                                                       float* __restrict__ out){
  // [0,64K): 2 dirs x 4 bufs x 8KB staging; [64K,72K): csc[2][32][32] f32.
  // Epilogue ebuf f32[2][256][36] = 73728 B aliases everything (post-loop).
  __shared__ __align__(16) char smem[73728];
  const int tid  = threadIdx.x;
  const int lane = tid & 63;
  const int w    = tid >> 6;            // 0..15
  const int dir  = w >> 3;              // waves 0-7 -> dir0; 8-15 -> dir1
  const int sub  = w & 7;               // row-32-group AND staging-chunk index
  const int lm   = lane & 15;
  const int kh   = lane >> 4;           // 0..3 (k-quad per K-half)
  const int s0   = blockIdx.x * 32;
  const int rb   = blockIdx.y;          // row-block == batch index i
  const int r0   = rb * 256;
  const int ib   = rb;                  // excluded diagonal j == i

  // dir0: rows Vq (scale 1/|V_i|F), cols Aq (scale 1/colnorm A); dir1 swapped.
  const unsigned char* rowmat = mats + (size_t)dir * SLOT;
  const unsigned char* colmat = mats + (size_t)(1 - dir) * SLOT;
  const float sivn = ivn[dir * 32 + ib] * 1.44269504088896340736f;  // * log2(e)

  char*  dbase = smem + dir * 32768;                  // this dir's 4 x 8KB bufs
  float* cscw  = (float*)(smem + 65536) + dir * 1024; // this dir's csc[32][32]
  const unsigned char* colbase = colmat + (size_t)s0 * 256;  // 8KB j-tile @ +j*65536
  const int lo16 = lane * 16;

  // Stage this wave's 1KB chunk of the dir's 8KB tile for col-tile x.
  auto issue = [&](int x){
    const int j = x + (x >= ib ? 1 : 0);
    glds16(colbase + (size_t)j * 65536 + sub * 1024 + lo16,
           dbase + ((x & 3) << 13) + sub * 1024 + lo16);
  };

  issue(0);
  issue(1);

  // Block-shared csc table (per dir): csc[j][col] = sivn * icn_col[j*256+s0+col].
  // 8 waves/dir x 64 lanes: each lane fills 2 entries.
  {
    const int col = lane & 31;
    const int jh  = lane >> 5;          // 0/1
    const float* ib2 = icn + (size_t)(1 - dir) * 8192 + s0 + col;
    #pragma unroll
    for (int jx = 0; jx < 2; ++jx){
      const int j = sub * 4 + jx * 2 + jh;
      cscw[j * 32 + col] = sivn * ib2[j * 256];
    }
  }

  // A-fragments: this wave's 32 rows (group sub of the 256-row block);
  // K-half t, 16B unit u at slot (t*8 + kh*2 + u) ^ lm. 32 regs, invariant.
  i32x8 afr[2][2];                      // [mi][K-half]
  #pragma unroll
  for (int mi = 0; mi < 2; ++mi){
    const unsigned char* rp = rowmat + (size_t)(r0 + sub * 32 + mi * 16 + lm) * 256;
    #pragma unroll
    for (int t = 0; t < 2; ++t){
      i32x4 lo = *(const i32x4*)(rp + ((((t << 3) | (kh << 1) | 0) ^ lm) << 4));
      i32x4 hi = *(const i32x4*)(rp + ((((t << 3) | (kh << 1) | 1) ^ lm) << 4));
      afr[mi][t] = i32x8{lo.x, lo.y, lo.z, lo.w, hi.x, hi.y, hi.z, hi.w};
    }
  }
  #pragma unroll
  for (int mi = 0; mi < 2; ++mi)
    #pragma unroll
    for (int t = 0; t < 2; ++t)
      asm volatile("" : "+v"(afr[mi][t]));

  // ds_read offsets: col-group nj -> tile row nj*16+lm ((row&15)==lm, same
  // XOR key as staging since s0 is a multiple of 32).
  int ad[2][2][2];                      // [nj][K-half][unit]
  #pragma unroll
  for (int nj = 0; nj < 2; ++nj)
    #pragma unroll
    for (int t = 0; t < 2; ++t)
      #pragma unroll
      for (int u = 0; u < 2; ++u)
        ad[nj][t][u] = (nj * 16 + lm) * 256 + ((((t << 3) | (kh << 1) | u) ^ lm) << 4);

  f32x4 acc[2][2];
  #pragma unroll
  for (int mi = 0; mi < 2; ++mi)
    #pragma unroll
    for (int nj = 0; nj < 2; ++nj)
      acc[mi][nj] = f32x4{0.f, 0.f, 0.f, 0.f};
  const f32x4 fz = {0.f, 0.f, 0.f, 0.f};   // hoisted zero C-operand for MFMA t=0

  // Drain prologue (csc gloads + afr + DMA(0),DMA(1) + csc LDS writes), sync.
  asm volatile("s_waitcnt vmcnt(0) lgkmcnt(0)" ::: "memory");
  __builtin_amdgcn_s_barrier();
  __builtin_amdgcn_sched_barrier(0);

  // vmcnt invariant at step start: {x+1} outstanding (1 op, from step x-1).
  #pragma unroll 1
  for (int x = 0; x < 31; ++x){
    const int j = x + (x >= ib ? 1 : 0);

    if (x <= 28) issue(x + 2);          // -> outstanding {x+1, x+2}

    const char* rbuf = dbase + ((x & 3) << 13);
    i32x8 b[2][2];                      // [K-half][nj]
    #pragma unroll
    for (int nj = 0; nj < 2; ++nj)
      #pragma unroll
      for (int t = 0; t < 2; ++t){
        i32x4 lo = *(const i32x4*)(rbuf + ad[nj][t][0]);
        i32x4 hi = *(const i32x4*)(rbuf + ad[nj][t][1]);
        b[t][nj] = i32x8{lo.x, lo.y, lo.z, lo.w, hi.x, hi.y, hi.z, hi.w};
      }
    const float csc0 = cscw[j * 32 + lm];
    const float csc1 = cscw[j * 32 + 16 + lm];

    f32x4 S[2][2];
    #pragma unroll
    for (int mi = 0; mi < 2; ++mi){
      S[mi][0] = __builtin_amdgcn_mfma_scale_f32_16x16x128_f8f6f4(afr[mi][0], b[0][0], fz, 0, 0, 0, 127, 0, 127);
      S[mi][1] = __builtin_amdgcn_mfma_scale_f32_16x16x128_f8f6f4(afr[mi][0], b[0][1], fz, 0, 0, 0, 127, 0, 127);
    }
    #pragma unroll
    for (int mi = 0; mi < 2; ++mi){
      S[mi][0] = __builtin_amdgcn_mfma_scale_f32_16x16x128_f8f6f4(afr[mi][1], b[1][0], S[mi][0], 0, 0, 0, 127, 0, 127);
      S[mi][1] = __builtin_amdgcn_mfma_scale_f32_16x16x128_f8f6f4(afr[mi][1], b[1][1], S[mi][1], 0, 0, 0, 127, 0, 127);
    }

    #pragma unroll
    for (int mi = 0; mi < 2; ++mi){
      const f32x4 t0 = S[mi][0] * csc0;
      const f32x4 t1 = S[mi][1] * csc1;
      f32x4 e0, e1;
      #pragma unroll
      for (int r = 0; r < 4; ++r){ e0[r] = __builtin_amdgcn_exp2f(t0[r]); e1[r] = __builtin_amdgcn_exp2f(t1[r]); }
      acc[mi][0] += e0;
      acc[mi][1] += e1;
    }

    // End-of-step: wait for DMA(x+1) only (the just-issued x+2 stays in
    // flight -> vmcnt(1)), then raw barrier (all 16 waves' chunks visible).
    if (x <= 28)      asm volatile("s_waitcnt vmcnt(1)" ::: "memory");
    else if (x == 29) asm volatile("s_waitcnt vmcnt(0)" ::: "memory");
    if (x < 30){
      __builtin_amdgcn_s_barrier();
      __builtin_amdgcn_sched_barrier(0);
    }
  }

  // Epilogue: per-dir log1p into LDS (aliases staging -- dead now), combine
  // dirs, coalesced store. C/D layout: col = lane&15, row = (lane>>4)*4+reg.
  __syncthreads();
  float* ebuf = (float*)smem;
  #pragma unroll
  for (int mi = 0; mi < 2; ++mi){
    #pragma unroll
    for (int nj = 0; nj < 2; ++nj){
      const int n = nj * 16 + lm;
      #pragma unroll
      for (int r = 0; r < 4; ++r){
        const int m = sub * 32 + mi * 16 + (kh << 2) + r;
        ebuf[(dir * 256 + m) * 36 + n] = __logf(1.f + acc[mi][nj][r]);
      }
    }
  }
  __syncthreads();
  #pragma unroll
  for (int p = 0; p < 2; ++p){
    const int i   = tid + p * 1024;    // 0..2047 (float4 units of the 256x32 tile)
    const int row = i >> 3;
    const int c4  = i & 7;
    const f32x4 e0 = *(const f32x4*)(&ebuf[row * 36 + c4 * 4]);
    const f32x4 e1 = *(const f32x4*)(&ebuf[(256 + row) * 36 + c4 * 4]);
    f32x4 o;
    #pragma unroll
    for (int e = 0; e < 4; ++e) o[e] = -(e0[e] + e1[e]);
    *(f32x4*)(&out[(size_t)(r0 + row) * 256 + s0 + c4 * 4]) = o;
  }
}

extern "C" void kernel_launch(void* const* d_in, const int* in_sizes, int n_in,
                              void* d_out, int out_size, void* d_ws, size_t ws_size,
                              hipStream_t stream){
  const float* V = (const float*)d_in[2];   // back_VF  (pre_VF/pre_AF unused by reference)
  const float* A = (const float*)d_in[3];   // back_AF
  float* out = (float*)d_out;
  float* ivn = (float*)((char*)d_ws + IVN_OFF);
  float* icn = (float*)((char*)d_ws + ICN_OFF);
  float* csq = (float*)((char*)d_ws + CSQ_OFF);
  unsigned char* mats = (unsigned char*)((char*)d_ws + MATS_OFF);

  cast_ns_k<<<dim3(8, 32, 2), 256, 0, stream>>>(V, A, mats, csq);
  nreduce_k<<<dim3(32, 2), 256, 0, stream>>>(csq, ivn, icn);
  gemm_both_k<<<dim3(8, 32), 1024, 0, stream>>>(mats, ivn, icn, out);
}

// Round 9
// 115.327 us; speedup vs baseline: 1.1439x; 1.0077x over previous
//
#include <hip/hip_runtime.h>
#include <cstdint>

// Problem constants: B=32, T=D=256, rows R = B*T = 8192, K = 256.
#define R_TOT 8192
#define KD    256
#define SLOT  ((size_t)R_TOT * KD)            // bytes per fp8 image (2,097,152)
// ws layout (bytes):  total ~4.8 MB
#define IVN_OFF  0                            // 64 f32: 1/frobenius-norm [ten][j]
#define ICN_OFF  256                          // 2*8192 f32: 1/col-norm [ten][j][s]
#define CSQ_OFF  (ICN_OFF + 65536)            // 8 tc-partials x 2*8192 f32 = 512 KB
#define MATS_OFF (CSQ_OFF + 524288)           // 2 fp8 images (Vq, Aq), swizzled, 4 MB

typedef float f32x4 __attribute__((ext_vector_type(4)));
typedef int   i32x4 __attribute__((ext_vector_type(4)));
typedef int   i32x8 __attribute__((ext_vector_type(8)));   // 32 fp8 = one MX MFMA operand

__device__ __forceinline__ void glds16(const void* g, void* l){
  __builtin_amdgcn_global_load_lds((const __attribute__((address_space(1))) uint32_t*)g,
                                   (__attribute__((address_space(3))) uint32_t*)l, 16, 0, 0);
}

// Image layout (R11-verbatim): plain k-order rows (256 B per image row r), 16B
// chunk c (k in [c*16, c*16+16)) stored at 16B slot c ^ (r & 15). XOR swizzle
// keeps MFMA-layout ds_read_b128 conflict-free (verified R7-R11).
__global__ void cast_ns_k(const float* __restrict__ V, const float* __restrict__ A,
                          unsigned char* __restrict__ mats, float* __restrict__ csq){
  const int tc = blockIdx.x, j = blockIdx.y, ten = blockIdx.z;
  const int tid = threadIdx.x;
  const int g    = tid & 31;                 // d-chunk of 8 floats = 8 fp8 bytes
  const int tsub = tid >> 5;                 // 0..7
  const int c    = g >> 1;                   // 16B chunk index 0..15
  const int half = g & 1;                    // which 8B half of the chunk
  const float* X = (ten ? A : V) + (size_t)j * 65536;
  unsigned char* M = mats + (size_t)ten * SLOT + (size_t)j * 65536;
  float cs[8];
  #pragma unroll
  for (int e = 0; e < 8; ++e) cs[e] = 0.f;
  #pragma unroll
  for (int tt = 0; tt < 4; ++tt){
    const int t = tc * 32 + tt * 8 + tsub;
    const float4 p0 = *(const float4*)(X + t * 256 + g * 8);
    const float4 p1 = *(const float4*)(X + t * 256 + g * 8 + 4);
    cs[0] += p0.x * p0.x; cs[1] += p0.y * p0.y; cs[2] += p0.z * p0.z; cs[3] += p0.w * p0.w;
    cs[4] += p1.x * p1.x; cs[5] += p1.y * p1.y; cs[6] += p1.z * p1.z; cs[7] += p1.w * p1.w;
    int d0 = __builtin_amdgcn_cvt_pk_fp8_f32(p0.x, p0.y, 0, false);
    d0     = __builtin_amdgcn_cvt_pk_fp8_f32(p0.z, p0.w, d0, true);
    int d1 = __builtin_amdgcn_cvt_pk_fp8_f32(p1.x, p1.y, 0, false);
    d1     = __builtin_amdgcn_cvt_pk_fp8_f32(p1.z, p1.w, d1, true);
    int2 o; o.x = d0; o.y = d1;
    *(int2*)(M + (size_t)t * 256 + (((c ^ (t & 15)) << 4) | (half << 3))) = o;
  }
  __shared__ float red[8][256];
  #pragma unroll
  for (int e = 0; e < 8; ++e) red[tsub][g * 8 + e] = cs[e];
  __syncthreads();
  float s = 0.f;
  #pragma unroll
  for (int gg = 0; gg < 8; ++gg) s += red[gg][tid];
  csq[(size_t)((tc * 2 + ten) * 32 + j) * 256 + tid] = s;
}

// Finish norms: sum 8 tc-partials; icn = rsqrt, ivn = rsqrt of row-sum. Grid (32, 2).
__global__ void nreduce_k(const float* __restrict__ csq, float* __restrict__ ivn,
                          float* __restrict__ icn){
  const int j = blockIdx.x, ten = blockIdx.y, s = threadIdx.x;
  float c = 0.f;
  #pragma unroll
  for (int tc = 0; tc < 8; ++tc)
    c += csq[(size_t)((tc * 2 + ten) * 32 + j) * 256 + s];
  icn[ten * 8192 + j * 256 + s] = rsqrtf(c + 1e-18f);
  __shared__ float red[256];
  red[s] = c; __syncthreads();
  for (int off = 128; off > 0; off >>= 1){
    if (s < off) red[s] += red[s + off];
    __syncthreads();
  }
  if (s == 0) ivn[ten * 32 + j] = rsqrtf(red[0] + 1e-18f);
}

// v22: fat waves + shared staging + TLP + block stagger.
// Diagnosis chain: v13 (fat 64-row waves, 4 waves/SIMD, private staging) =
// 44.8; v21 (32-row waves, 4/SIMD, shared staging, 1 block/CU) ~= 43-45.
// v21's flaw: halving wave height DOUBLED LDS-read per MFMA (32-row wave
// reads the same 8KB B-tile as a 64-row wave for half the work): per-CU
// per-step LDS = 128KB ~= 1000cy ~ MFMA 1104cy, and the 16-wave barrier
// locksteps everyone into bursting that queue simultaneously.
// v22: 64-row waves (4KB LDS read per 8 MFMA, v13 ratio; afr 64 regs,
// ~128-reg wave -> 4 waves/SIMD), 16-col tiles, block = 512 thr = 2 dirs x
// 4 waves x 64 rows = one batch i x 16 cols. Grid 16x32 = 512 = 2
// independent blocks/CU (barrier spans only 8 waves; blocks phase-stagger).
// Staged = 512 x 31 x 8KB = 127 MB (4x cut vs v13). Each wave stages 1KB
// (one glds16)/step, depth-2 prefetch, invariant-exact vmcnt(1), raw
// s_barrier (never vmcnt(0) mid-loop). Per-CU per-step: LDS read 64KB
// (~500cy) << MFMA 1104cy. Spill detector: WRITE_SIZE (clean = 8MB).
__global__ __launch_bounds__(512, 4) void gemm_both_k(const unsigned char* __restrict__ mats,
                                                      const float* __restrict__ ivn,
                                                      const float* __restrict__ icn,
                                                      float* __restrict__ out){
  // [0,32K): 2 dirs x 4 bufs x 4KB staging; [32K,36K): csc[2][32][16] f32.
  // Epilogue ebuf f32[2][256][20] = 40960 B aliases everything (post-loop).
  __shared__ __align__(16) char smem[40960];
  const int tid  = threadIdx.x;
  const int lane = tid & 63;
  const int w    = tid >> 6;            // 0..7
  const int dir  = w >> 2;              // waves 0-3 -> dir0; 4-7 -> dir1
  const int sub  = w & 3;               // row-64-group AND staging-chunk index
  const int lm   = lane & 15;
  const int kh   = lane >> 4;           // 0..3 (k-quad per K-half)
  const int s0   = blockIdx.x * 16;     // 16-col tile
  const int rb   = blockIdx.y;          // row-block == batch index i
  const int r0   = rb * 256;
  const int ib   = rb;                  // excluded diagonal j == i

  // dir0: rows Vq (scale 1/|V_i|F), cols Aq (scale 1/colnorm A); dir1 swapped.
  const unsigned char* rowmat = mats + (size_t)dir * SLOT;
  const unsigned char* colmat = mats + (size_t)(1 - dir) * SLOT;
  const float sivn = ivn[dir * 32 + ib] * 1.44269504088896340736f;  // * log2(e)

  char*  dbase = smem + dir * 16384;                  // this dir's 4 x 4KB bufs
  float* cscw  = (float*)(smem + 32768) + dir * 512;  // this dir's csc[32][16]
  const unsigned char* colbase = colmat + (size_t)s0 * 256;  // 4KB j-tile @ +j*65536
  const int lo16 = lane * 16;

  // Stage this wave's 1KB chunk of the dir's 4KB tile for col-tile x.
  auto issue = [&](int x){
    const int j = x + (x >= ib ? 1 : 0);
    glds16(colbase + (size_t)j * 65536 + sub * 1024 + lo16,
           dbase + ((x & 3) << 12) + sub * 1024 + lo16);
  };

  issue(0);
  issue(1);

  // Block-shared csc table (per dir): csc[j][col] = sivn * icn_col[j*256+s0+col].
  // 4 waves/dir: wave covers j rows sub*8 .. sub*8+7 (kh picks within 4).
  {
    const float* ib2 = icn + (size_t)(1 - dir) * 8192 + s0 + lm;
    #pragma unroll
    for (int jx = 0; jx < 2; ++jx){
      const int j = sub * 8 + jx * 4 + kh;
      cscw[j * 16 + lm] = sivn * ib2[j * 256];
    }
  }

  // A-fragments: this wave's 64 rows (group sub of the 256-row block);
  // K-half t, 16B unit u at slot (t*8 + kh*2 + u) ^ lm. 64 regs, invariant.
  i32x8 afr[4][2];                      // [mi][K-half]
  #pragma unroll
  for (int mi = 0; mi < 4; ++mi){
    const unsigned char* rp = rowmat + (size_t)(r0 + sub * 64 + mi * 16 + lm) * 256;
    #pragma unroll
    for (int t = 0; t < 2; ++t){
      i32x4 lo = *(const i32x4*)(rp + ((((t << 3) | (kh << 1) | 0) ^ lm) << 4));
      i32x4 hi = *(const i32x4*)(rp + ((((t << 3) | (kh << 1) | 1) ^ lm) << 4));
      afr[mi][t] = i32x8{lo.x, lo.y, lo.z, lo.w, hi.x, hi.y, hi.z, hi.w};
    }
  }
  #pragma unroll
  for (int mi = 0; mi < 4; ++mi)
    #pragma unroll
    for (int t = 0; t < 2; ++t)
      asm volatile("" : "+v"(afr[mi][t]));

  // ds_read offsets: tile row lm (16 rows = 16 cols of sim), K-half t, unit
  // u; (row&15)==lm so the XOR key matches staging (s0 multiple of 16).
  int ad[2][2];                         // [K-half][unit]
  #pragma unroll
  for (int t = 0; t < 2; ++t)
    #pragma unroll
    for (int u = 0; u < 2; ++u)
      ad[t][u] = lm * 256 + ((((t << 3) | (kh << 1) | u) ^ lm) << 4);

  f32x4 acc[4];
  #pragma unroll
  for (int mi = 0; mi < 4; ++mi)
    acc[mi] = f32x4{0.f, 0.f, 0.f, 0.f};
  const f32x4 fz = {0.f, 0.f, 0.f, 0.f};   // hoisted zero C-operand for MFMA t=0

  // Drain prologue (csc gloads + afr + DMA(0),DMA(1) + csc LDS writes), sync.
  asm volatile("s_waitcnt vmcnt(0) lgkmcnt(0)" ::: "memory");
  __builtin_amdgcn_s_barrier();
  __builtin_amdgcn_sched_barrier(0);

  // vmcnt invariant at step-x start: outstanding = {x+1} (per wave).
  #pragma unroll 1
  for (int x = 0; x < 31; ++x){
    const int j = x + (x >= ib ? 1 : 0);

    if (x <= 28) issue(x + 2);          // -> outstanding {x+1, x+2}

    const char* rbuf = dbase + ((x & 3) << 12);
    i32x8 b[2];                         // [K-half]
    #pragma unroll
    for (int t = 0; t < 2; ++t){
      i32x4 lo = *(const i32x4*)(rbuf + ad[t][0]);
      i32x4 hi = *(const i32x4*)(rbuf + ad[t][1]);
      b[t] = i32x8{lo.x, lo.y, lo.z, lo.w, hi.x, hi.y, hi.z, hi.w};
    }
    const float csc = cscw[j * 16 + lm];

    f32x4 S[4];
    #pragma unroll
    for (int mi = 0; mi < 4; ++mi)
      S[mi] = __builtin_amdgcn_mfma_scale_f32_16x16x128_f8f6f4(afr[mi][0], b[0], fz, 0, 0, 0, 127, 0, 127);
    #pragma unroll
    for (int mi = 0; mi < 4; ++mi)
      S[mi] = __builtin_amdgcn_mfma_scale_f32_16x16x128_f8f6f4(afr[mi][1], b[1], S[mi], 0, 0, 0, 127, 0, 127);

    #pragma unroll
    for (int mi = 0; mi < 4; ++mi){
      const f32x4 t0 = S[mi] * csc;
      f32x4 e0;
      #pragma unroll
      for (int r = 0; r < 4; ++r) e0[r] = __builtin_amdgcn_exp2f(t0[r]);
      acc[mi] += e0;
    }

    // End-of-step: ensure DMA(x+1) landed (x+2 stays in flight -> vmcnt(1)),
    // then raw barrier so all 8 waves' chunks are visible.
    if (x <= 28)      asm volatile("s_waitcnt vmcnt(1)" ::: "memory");
    else if (x == 29) asm volatile("s_waitcnt vmcnt(0)" ::: "memory");
    if (x < 30){
      __builtin_amdgcn_s_barrier();
      __builtin_amdgcn_sched_barrier(0);
    }
  }

  // Epilogue: per-dir log1p into LDS (aliases staging -- dead now), combine
  // dirs, coalesced store. C/D layout: col = lane&15, row = (lane>>4)*4+reg.
  __syncthreads();
  float* ebuf = (float*)smem;
  #pragma unroll
  for (int mi = 0; mi < 4; ++mi){
    #pragma unroll
    for (int r = 0; r < 4; ++r){
      const int m = sub * 64 + mi * 16 + (kh << 2) + r;
      ebuf[(dir * 256 + m) * 20 + lm] = __logf(1.f + acc[mi][r]);
    }
  }
  __syncthreads();
  #pragma unroll
  for (int p = 0; p < 2; ++p){
    const int i   = tid + p * 512;     // 0..1023 (float4 units of the 256x16 tile)
    const int row = i >> 2;
    const int c4  = i & 3;
    const f32x4 e0 = *(const f32x4*)(&ebuf[row * 20 + c4 * 4]);
    const f32x4 e1 = *(const f32x4*)(&ebuf[(256 + row) * 20 + c4 * 4]);
    f32x4 o;
    #pragma unroll
    for (int e = 0; e < 4; ++e) o[e] = -(e0[e] + e1[e]);
    *(f32x4*)(&out[(size_t)(r0 + row) * 256 + s0 + c4 * 4]) = o;
  }
}

extern "C" void kernel_launch(void* const* d_in, const int* in_sizes, int n_in,
                              void* d_out, int out_size, void* d_ws, size_t ws_size,
                              hipStream_t stream){
  const float* V = (const float*)d_in[2];   // back_VF  (pre_VF/pre_AF unused by reference)
  const float* A = (const float*)d_in[3];   // back_AF
  float* out = (float*)d_out;
  float* ivn = (float*)((char*)d_ws + IVN_OFF);
  float* icn = (float*)((char*)d_ws + ICN_OFF);
  float* csq = (float*)((char*)d_ws + CSQ_OFF);
  unsigned char* mats = (unsigned char*)((char*)d_ws + MATS_OFF);

  cast_ns_k<<<dim3(8, 32, 2), 256, 0, stream>>>(V, A, mats, csq);
  nreduce_k<<<dim3(32, 2), 256, 0, stream>>>(csq, ivn, icn);
  gemm_both_k<<<dim3(16, 32), 512, 0, stream>>>(mats, ivn, icn, out);
}